// Round 11
// baseline (189.103 us; speedup 1.0000x reference)
//
#include <hip/hip_runtime.h>
#include <hip/hip_bf16.h>
#include <math.h>

#define H_    16
#define DK_   64
#define Dm    1024
#define Bb    2
#define Ss    2048
#define Mrows 4096   // B*S
#define QSCALE 0.1803368801f   // (1/8) * log2(e): flash softmax runs in exp2 domain

typedef short s16x8 __attribute__((ext_vector_type(8)));
typedef float f32x4 __attribute__((ext_vector_type(4)));
typedef unsigned short u16;
typedef unsigned int u32;

__device__ __forceinline__ u16 f2b(float f) {
  __hip_bfloat16 h = __float2bfloat16(f);
  return *reinterpret_cast<u16*>(&h);
}
__device__ __forceinline__ float b2f(u16 u) {
  __hip_bfloat16 h;
  *reinterpret_cast<u16*>(&h) = u;
  return __bfloat162float(h);
}
// pack two fp32 -> (bf16(hi)<<16)|bf16(lo) by truncation: ONE v_perm_b32
__device__ __forceinline__ u32 pkbf(float hi, float lo) {
  return __builtin_amdgcn_perm(__float_as_uint(hi), __float_as_uint(lo), 0x07060302u);
}

// async global->LDS, 16B per lane; LDS dest = wave-uniform base + lane*16
#define GLDS(g, l)                                                             \
  __builtin_amdgcn_global_load_lds(                                            \
      (const __attribute__((address_space(1))) unsigned int*)(g),              \
      (__attribute__((address_space(3))) unsigned int*)(l), 16, 0, 0)

// XOR-swizzle for [rows][64] u16 tiles, 16B-chunk granular
__device__ __forceinline__ int SW64(int row, int col) {
  return row * 64 + ((((col >> 3) ^ (row & 7) ^ (row >> 3)) & 7) << 3) + (col & 7);
}

// ---------------------------------------------------------------- casts + rope table, one launch
__global__ __launch_bounds__(256) void k_castall(
    const float* __restrict__ x,  const float* __restrict__ Wq,
    const float* __restrict__ Wk, const float* __restrict__ Wv,
    const float* __restrict__ Wo,
    u16* __restrict__ xb,  u16* __restrict__ wqb, u16* __restrict__ wkb,
    u16* __restrict__ wvb, u16* __restrict__ wob,
    const int* __restrict__ pos, float2* __restrict__ tab) {
  if (blockIdx.x >= 8192) {
    int t = (blockIdx.x - 8192) * 256 + threadIdx.x;   // 65536
    int s = t >> 5, i = t & 31;
    float p = (float)pos[s];
    float ang = p * powf(10000.0f, -(float)i / 32.0f);
    tab[t] = make_float2(cosf(ang), sinf(ang));
    return;
  }
  int i = blockIdx.x * 256 + threadIdx.x;        // 2M float4 total
  const float* s;
  u16* d;
  int off;
  if (i < 1048576) { s = x; d = xb; off = i; }
  else {
    int j = i - 1048576;
    int w = j >> 18;
    off = j & 262143;
    s = (w == 0) ? Wq : (w == 1) ? Wk : (w == 2) ? Wv : Wo;
    d = (w == 0) ? wqb : (w == 1) ? wkb : (w == 2) ? wvb : wob;
  }
  float4 v = reinterpret_cast<const float4*>(s)[off];
  ushort4 o;
  o.x = f2b(v.x); o.y = f2b(v.y); o.z = f2b(v.z); o.w = f2b(v.w);
  reinterpret_cast<ushort4*>(d)[off] = o;
}

// ---------------------------------------------------------------- RoPE apply on K only
__global__ __launch_bounds__(256) void k_ropeK(u16* __restrict__ K,
                                               const float2* __restrict__ tab) {
  int t = blockIdx.x * 256 + threadIdx.x;        // Mrows*Dm/8
  int row = t >> 7;
  int c0 = (t & 127) << 3;
  int i0 = (c0 & 63) >> 1;
  const float2* tb = &tab[(row & (Ss - 1)) * 32 + i0];
  float2 cs[4];
#pragma unroll
  for (int j = 0; j < 4; ++j) cs[j] = tb[j];
  size_t off = (size_t)row * Dm + c0;
  s16x8 k = *reinterpret_cast<const s16x8*>(&K[off]);
  s16x8 ko;
#pragma unroll
  for (int j = 0; j < 4; ++j) {
    float ke = b2f((u16)k[2 * j]), kd = b2f((u16)k[2 * j + 1]);
    ko[2 * j]     = (short)f2b(cs[j].x * ke - cs[j].y * kd);
    ko[2 * j + 1] = (short)f2b(cs[j].y * ke + cs[j].x * kd);
  }
  *reinterpret_cast<s16x8*>(&K[off]) = ko;
}

// ---------------------------------------------------------------- C = A * B^T, double-buffered
// 128xBN tile, BK=32, one barrier per iter. 16B-chunk swizzle.
// QKV=true: B = merged [3072][1024]; epilogue routes by n0>>10
// (0->Q, 1->K, 2->V transposed [b][e][s]). QKV=false: fp32 to OF.
template <int BN, bool QKV>
__global__ __launch_bounds__(256) void k_gemm(
    const u16* __restrict__ A, const u16* __restrict__ B,
    u16* __restrict__ OQ, u16* __restrict__ OK2, u16* __restrict__ OVT,
    float* __restrict__ OF, int K) {
  constexpr int NFR = BN / 32;
  __shared__ __align__(16) u16 lsA[2][128 * 32];
  __shared__ __align__(16) u16 lsB[2][BN * 32];
  const int tid = threadIdx.x, lane = tid & 63, wave = tid >> 6;
  const int quad = lane >> 4, l16 = lane & 15;
  const int wrow = wave >> 1, wcol = wave & 1;
  const int n0 = blockIdx.x * BN, m0 = blockIdx.y * 128;
  f32x4 acc[4][NFR] = {};

  auto stage = [&](int k0, int bi) {
#pragma unroll
    for (int c = 0; c < 2; ++c) {
      int f = (wave * 2 + c) * 64 + lane;
      int row = f >> 2;
      int gs = (f & 3) ^ ((row >> 1) & 3);
      GLDS(A + (size_t)(m0 + row) * K + k0 + gs * 8, &lsA[bi][(wave * 2 + c) * 512]);
    }
#pragma unroll
    for (int c = 0; c < NFR / 2; ++c) {
      int f = (wave * (NFR / 2) + c) * 64 + lane;
      int row = f >> 2;
      int gs = (f & 3) ^ ((row >> 1) & 3);
      GLDS(B + (size_t)(n0 + row) * K + k0 + gs * 8, &lsB[bi][(wave * (NFR / 2) + c) * 512]);
    }
  };

  stage(0, 0);
  int bi = 0;
  for (int k0 = 0; k0 < K; k0 += 32) {
    __syncthreads();
    if (k0 + 32 < K) stage(k0 + 32, bi ^ 1);
    s16x8 af[4], bfr[NFR];
#pragma unroll
    for (int i = 0; i < 4; ++i) {
      int row = wrow * 64 + i * 16 + l16;
      af[i] = *reinterpret_cast<const s16x8*>(
          &lsA[bi][row * 32 + ((quad ^ ((row >> 1) & 3)) << 3)]);
    }
#pragma unroll
    for (int i = 0; i < NFR; ++i) {
      int row = wcol * (BN / 2) + i * 16 + l16;
      bfr[i] = *reinterpret_cast<const s16x8*>(
          &lsB[bi][row * 32 + ((quad ^ ((row >> 1) & 3)) << 3)]);
    }
#pragma unroll
    for (int mi = 0; mi < 4; ++mi)
#pragma unroll
      for (int ni = 0; ni < NFR; ++ni)
        acc[mi][ni] = __builtin_amdgcn_mfma_f32_16x16x32_bf16(af[mi], bfr[ni], acc[mi][ni], 0, 0, 0);
    bi ^= 1;
  }

  if (QKV) {
    const int which = n0 >> 10;
    const int nbase = (n0 & 1023) + wcol * (BN / 2);
    if (which == 2) {
#pragma unroll
      for (int mi = 0; mi < 4; ++mi)
#pragma unroll
        for (int ni = 0; ni < NFR; ++ni) {
          int row0 = m0 + wrow * 64 + mi * 16 + quad * 4;
          int col  = nbase + ni * 16 + l16;
          int bb = row0 >> 11, s0 = row0 & (Ss - 1);
          ushort4 pk;
          pk.x = f2b(acc[mi][ni][0]); pk.y = f2b(acc[mi][ni][1]);
          pk.z = f2b(acc[mi][ni][2]); pk.w = f2b(acc[mi][ni][3]);
          *reinterpret_cast<ushort4*>(&OVT[((size_t)bb * Dm + col) * Ss + s0]) = pk;
        }
    } else {
      u16* Op = which ? OK2 : OQ;
#pragma unroll
      for (int mi = 0; mi < 4; ++mi)
#pragma unroll
        for (int ni = 0; ni < NFR; ++ni)
#pragma unroll
          for (int r = 0; r < 4; ++r) {
            int row = m0 + wrow * 64 + mi * 16 + quad * 4 + r;
            int col = nbase + ni * 16 + l16;
            Op[(size_t)row * Dm + col] = f2b(acc[mi][ni][r]);
          }
    }
  } else {
#pragma unroll
    for (int mi = 0; mi < 4; ++mi)
#pragma unroll
      for (int ni = 0; ni < NFR; ++ni)
#pragma unroll
        for (int r = 0; r < 4; ++r) {
          int row = m0 + wrow * 64 + mi * 16 + quad * 4 + r;
          int col = n0 + wcol * (BN / 2) + ni * 16 + l16;
          OF[(size_t)row * Dm + col] = acc[mi][ni][r];
        }
  }
}

// ---------------------------------------------------------------- flash attention (causal, key-split)
// Static-max softmax (exp2 domain) makes partials LINEAR: ot and l just add.
// 768 blocks = per (b,h): qt<8 -> one block (tiles [0,2qt+2)); qt>=8 -> two
// blocks: part0 [0,qt+1), part1 [qt+1,2qt+2), fp32 partials to workspace.
// Item table: bid=item*32+bh; item j / j+8 / j+16 (co-resident triple) =
// single qt=j + both halves of qt=15-j -> every triple = exactly 34 tiles.
// Single-tile dbuf staging (48 KB LDS -> 3 blocks/CU). Q-RoPE fused.
__global__ __launch_bounds__(256) void k_flash(const u16* __restrict__ Q,
                                               const u16* __restrict__ K,
                                               const u16* __restrict__ VT,
                                               u16* __restrict__ O,
                                               float* __restrict__ Pp_all,
                                               float* __restrict__ Lp_all,
                                               const float2* __restrict__ tab) {
  __shared__ __align__(16) u16 lsK[2][64 * 64];    // [buf][key][dk], SW64
  __shared__ __align__(16) u16 lsVT[2][64 * 64];   // [buf][dk][key], SW64
  __shared__ __align__(16) u16 lsP[4][32 * 64];    // per-wave P^T [q][key], chunk-xor
  const int tid = threadIdx.x, lane = tid & 63, wave = tid >> 6;
  const int quad = lane >> 4, l16 = lane & 15;
  const int bid = blockIdx.x;                      // 768 blocks
  const int bh = bid & 31, item = bid >> 5;
  const int h = bh & (H_ - 1), b = bh >> 4;
  const int j = item & 7, grp = item >> 3;         // 0=single, 1=part0, 2=part1
  const int qt = (grp == 0) ? j : (15 - j);
  const int kt_lo = (grp == 2) ? (qt + 1) : 0;
  const int kt_hi = (grp == 1) ? (qt + 1) : (2 * qt + 2);
  const int qbase = qt * 128 + wave * 32;
  const int ktmax_w = (qbase + 31) >> 6;           // diagonal tile for this wave
  const int xorv = (l16 * 2) & 0xE;

  // Q frags with fused RoPE (+QSCALE): 4 in-lane even/odd pairs per 8-dk chunk
  s16x8 qf[2][2];
#pragma unroll
  for (int s = 0; s < 2; ++s) {
    const int qpos = qbase + s * 16 + l16;
    const size_t qoff = (size_t)(b * Ss + qpos) * Dm + h * 64;
    s16x8 r0 = *reinterpret_cast<const s16x8*>(&Q[qoff + quad * 8]);
    s16x8 r1 = *reinterpret_cast<const s16x8*>(&Q[qoff + 32 + quad * 8]);
    const float2* tb = &tab[(qpos & (Ss - 1)) * 32];
#pragma unroll
    for (int kc = 0; kc < 2; ++kc) {
      s16x8 raw = kc ? r1 : r0;
#pragma unroll
      for (int p = 0; p < 4; ++p) {
        float2 cs = tb[kc * 16 + quad * 4 + p];
        float e = b2f((u16)raw[2 * p]), o = b2f((u16)raw[2 * p + 1]);
        qf[s][kc][2 * p]     = (short)f2b((cs.x * e - cs.y * o) * QSCALE);
        qf[s][kc][2 * p + 1] = (short)f2b((cs.y * e + cs.x * o) * QSCALE);
      }
    }
  }
  s16x8 ones;
#pragma unroll
  for (int jj = 0; jj < 8; ++jj) ones[jj] = (short)0x3F80;   // bf16 1.0

  f32x4 ot[2][4] = {};
  f32x4 lAcc[2] = {};

  auto stage = [&](int kt, int bi) {
    const size_t kbase  = (size_t)(b * Ss + kt * 64) * Dm + h * 64;
    const size_t vtbase = ((size_t)b * Dm + h * 64) * Ss + kt * 64;
#pragma unroll
    for (int c = 0; c < 2; ++c) {
      int sl = (wave * 2 + c) * 64 + lane;
      int row = sl >> 3;
      int gg = ((sl & 7) ^ (row & 7) ^ (row >> 3)) & 7;
      GLDS(K  + kbase  + (size_t)row * Dm + gg * 8, &lsK[bi][(wave * 2 + c) * 512]);
      GLDS(VT + vtbase + (size_t)row * Ss + gg * 8, &lsVT[bi][(wave * 2 + c) * 512]);
    }
  };

  stage(kt_lo, 0);
  int bi = 0;
  for (int kt = kt_lo; kt < kt_hi; ++kt) {
    __syncthreads();
    if (kt + 1 < kt_hi) stage(kt + 1, bi ^ 1);
    if (kt > ktmax_w) { bi ^= 1; continue; }       // wave-uniform skip (diag blocks)

    f32x4 st[2][4] = {};
#pragma unroll
    for (int kc = 0; kc < 2; ++kc)
#pragma unroll
      for (int ni = 0; ni < 4; ++ni) {
        s16x8 kf = *reinterpret_cast<const s16x8*>(
            &lsK[bi][SW64(ni * 16 + l16, kc * 32 + quad * 8)]);
        st[0][ni] = __builtin_amdgcn_mfma_f32_16x16x32_bf16(kf, qf[0][kc], st[0][ni], 0, 0, 0);
        st[1][ni] = __builtin_amdgcn_mfma_f32_16x16x32_bf16(kf, qf[1][kc], st[1][ni], 0, 0, 0);
      }
    if (kt == ktmax_w) {   // causal mask on diagonal tile: key > q
#pragma unroll
      for (int s = 0; s < 2; ++s) {
        int gq = qbase + s * 16 + l16;
#pragma unroll
        for (int ni = 0; ni < 4; ++ni)
#pragma unroll
          for (int r = 0; r < 4; ++r)
            if (kt * 64 + ni * 16 + quad * 4 + r > gq) st[s][ni][r] = -INFINITY;
      }
    }
#pragma unroll
    for (int s = 0; s < 2; ++s)
#pragma unroll
      for (int ni = 0; ni < 4; ++ni) {
        float e0 = __builtin_amdgcn_exp2f(st[s][ni][0]);
        float e1 = __builtin_amdgcn_exp2f(st[s][ni][1]);
        float e2 = __builtin_amdgcn_exp2f(st[s][ni][2]);
        float e3 = __builtin_amdgcn_exp2f(st[s][ni][3]);
        uint2 pk;
        pk.x = pkbf(e1, e0);
        pk.y = pkbf(e3, e2);
        *reinterpret_cast<uint2*>(
            &lsP[wave][(s * 16 + l16) * 64 + (((ni * 4 + quad) ^ xorv) << 2)]) = pk;
      }
#pragma unroll
    for (int kc = 0; kc < 2; ++kc) {
      s16x8 pf0 = *reinterpret_cast<const s16x8*>(
          &lsP[wave][l16 * 64 + (((kc * 8 + quad * 2) ^ xorv) << 2)]);
      s16x8 pf1 = *reinterpret_cast<const s16x8*>(
          &lsP[wave][(16 + l16) * 64 + (((kc * 8 + quad * 2) ^ xorv) << 2)]);
      lAcc[0] = __builtin_amdgcn_mfma_f32_16x16x32_bf16(ones, pf0, lAcc[0], 0, 0, 0);
      lAcc[1] = __builtin_amdgcn_mfma_f32_16x16x32_bf16(ones, pf1, lAcc[1], 0, 0, 0);
#pragma unroll
      for (int ni = 0; ni < 4; ++ni) {
        s16x8 vf = *reinterpret_cast<const s16x8*>(
            &lsVT[bi][SW64(ni * 16 + l16, kc * 32 + quad * 8)]);
        ot[0][ni] = __builtin_amdgcn_mfma_f32_16x16x32_bf16(vf, pf0, ot[0][ni], 0, 0, 0);
        ot[1][ni] = __builtin_amdgcn_mfma_f32_16x16x32_bf16(vf, pf1, ot[1][ni], 0, 0, 0);
      }
    }
    bi ^= 1;
  }

  if (grp == 0) {
    // single block: normalize + bf16 epilogue
#pragma unroll
    for (int s = 0; s < 2; ++s) {
      float inv = 1.0f / lAcc[s][0];
      const size_t obase = (size_t)(b * Ss + qbase + s * 16 + l16) * Dm + h * 64;
#pragma unroll
      for (int ni = 0; ni < 4; ++ni) {
        ushort4 pk;
        pk.x = f2b(ot[s][ni][0] * inv); pk.y = f2b(ot[s][ni][1] * inv);
        pk.z = f2b(ot[s][ni][2] * inv); pk.w = f2b(ot[s][ni][3] * inv);
        *reinterpret_cast<ushort4*>(&O[obase + ni * 16 + quad * 4]) = pk;
      }
    }
  } else {
    // split half: fp32 partial [128][64] + l[128] to workspace
    const int unit = (grp - 1) * 256 + bh * 8 + j;
    float* Pp = Pp_all + (size_t)unit * 8192;
    float* Lp = Lp_all + unit * 128;
#pragma unroll
    for (int s = 0; s < 2; ++s) {
      int qlocal = wave * 32 + s * 16 + l16;
#pragma unroll
      for (int ni = 0; ni < 4; ++ni)
        *reinterpret_cast<f32x4*>(&Pp[qlocal * 64 + ni * 16 + quad * 4]) = ot[s][ni];
      if (quad == 0) Lp[qlocal] = lAcc[s][0];
    }
  }
}

// ---------------------------------------------------------------- combine split partials
// unit u: bh = u>>3, j = u&7, qt = 15-j. O = (Pa+Pb)/(la+lb), bf16 out.
__global__ __launch_bounds__(256) void k_combine(const float* __restrict__ Pp_all,
                                                 const float* __restrict__ Lp_all,
                                                 u16* __restrict__ O) {
  const int u = blockIdx.x;                        // 256 units
  const int bh = u >> 3, j = u & 7, qt = 15 - j;
  const int h = bh & (H_ - 1), b = bh >> 4;
  const float* pa = Pp_all + (size_t)u * 8192;
  const float* pb = pa + (size_t)256 * 8192;
  const float* la = Lp_all + u * 128;
  const float* lb = la + 256 * 128;
#pragma unroll
  for (int it = 0; it < 8; ++it) {
    int idx = it * 1024 + threadIdx.x * 4;
    int q = idx >> 6, dk = idx & 63;
    float4 va = *reinterpret_cast<const float4*>(pa + idx);
    float4 vb = *reinterpret_cast<const float4*>(pb + idx);
    float inv = 1.0f / (la[q] + lb[q]);
    ushort4 pk;
    pk.x = f2b((va.x + vb.x) * inv); pk.y = f2b((va.y + vb.y) * inv);
    pk.z = f2b((va.z + vb.z) * inv); pk.w = f2b((va.w + vb.w) * inv);
    int gq = qt * 128 + q;
    *reinterpret_cast<ushort4*>(&O[(size_t)(b * Ss + gq) * Dm + h * 64 + dk]) = pk;
  }
}

// ---------------------------------------------------------------- launch
extern "C" void kernel_launch(void* const* d_in, const int* in_sizes, int n_in,
                              void* d_out, int out_size, void* d_ws, size_t ws_size,
                              hipStream_t stream) {
  const float* x  = (const float*)d_in[0];
  const float* Wq = (const float*)d_in[1];
  const float* Wk = (const float*)d_in[2];
  const float* Wv = (const float*)d_in[3];
  const float* Wo = (const float*)d_in[4];
  const int* pos  = (const int*)d_in[5];
  float* out = (float*)d_out;

  char* w = (char*)d_ws;
  u16* xb  = (u16*)w; w += (size_t)Mrows * Dm * 2;
  u16* wqb = (u16*)w; w += (size_t)Dm * Dm * 2;   // wqb/wkb/wvb contiguous:
  u16* wkb = (u16*)w; w += (size_t)Dm * Dm * 2;   // merged [3072][1024] B matrix
  u16* wvb = (u16*)w; w += (size_t)Dm * Dm * 2;
  u16* wob = (u16*)w; w += (size_t)Dm * Dm * 2;
  u16* Qb  = (u16*)w; w += (size_t)Mrows * Dm * 2;
  u16* Kb  = (u16*)w; w += (size_t)Mrows * Dm * 2;
  u16* VTb = (u16*)w; w += (size_t)Mrows * Dm * 2;   // V transposed [b][e][s]
  u16* Ab  = (u16*)w; w += (size_t)Mrows * Dm * 2;
  float2* tabf = (float2*)w; w += (size_t)Ss * 32 * sizeof(float2);
  float* Pp = (float*)w; w += (size_t)512 * 8192 * 4;   // 16 MB split partials
  float* Lp = (float*)w; w += (size_t)512 * 128 * 4;

  // casts + rope table in one launch
  k_castall<<<8448, 256, 0, stream>>>(x, Wq, Wk, Wv, Wo, xb, wqb, wkb, wvb, wob,
                                      pos, tabf);
  // merged QKV projection: B=[3072][1024], epilogue routes Q/K/V^T by n-tile
  k_gemm<128, true><<<dim3(24, 32), 256, 0, stream>>>(xb, wqb, Qb, Kb, VTb, nullptr, Dm);
  // RoPE on K only (Q's RoPE fused into flash)
  k_ropeK<<<Mrows * Dm / 8 / 256, 256, 0, stream>>>(Kb, tabf);
  // key-split flash + combine
  k_flash<<<dim3(768), 256, 0, stream>>>(Qb, Kb, VTb, Ab, Pp, Lp, tabf);
  k_combine<<<dim3(256), 256, 0, stream>>>(Pp, Lp, Ab);
  // output projection, fp32 epilogue
  k_gemm<64, false><<<dim3(16, 32), 256, 0, stream>>>(Ab, wob, nullptr, nullptr, nullptr, out, Dm);
}

// Round 12
// 186.648 us; speedup vs baseline: 1.0132x; 1.0132x over previous
//
#include <hip/hip_runtime.h>
#include <hip/hip_bf16.h>
#include <math.h>

#define H_    16
#define DK_   64
#define Dm    1024
#define Bb    2
#define Ss    2048
#define Mrows 4096   // B*S
#define QSCALE 0.1803368801f   // (1/8) * log2(e): flash softmax runs in exp2 domain

typedef short s16x8 __attribute__((ext_vector_type(8)));
typedef float f32x4 __attribute__((ext_vector_type(4)));
typedef unsigned short u16;
typedef unsigned int u32;

__device__ __forceinline__ u16 f2b(float f) {
  __hip_bfloat16 h = __float2bfloat16(f);
  return *reinterpret_cast<u16*>(&h);
}
__device__ __forceinline__ float b2f(u16 u) {
  __hip_bfloat16 h;
  *reinterpret_cast<u16*>(&h) = u;
  return __bfloat162float(h);
}
// pack two fp32 -> (bf16(hi)<<16)|bf16(lo) by truncation: ONE v_perm_b32
__device__ __forceinline__ u32 pkbf(float hi, float lo) {
  return __builtin_amdgcn_perm(__float_as_uint(hi), __float_as_uint(lo), 0x07060302u);
}

// async global->LDS, 16B per lane; LDS dest = wave-uniform base + lane*16
#define GLDS(g, l)                                                             \
  __builtin_amdgcn_global_load_lds(                                            \
      (const __attribute__((address_space(1))) unsigned int*)(g),              \
      (__attribute__((address_space(3))) unsigned int*)(l), 16, 0, 0)

// XOR-swizzle for [rows][64] u16 tiles, 16B-chunk granular
__device__ __forceinline__ int SW64(int row, int col) {
  return row * 64 + ((((col >> 3) ^ (row & 7) ^ (row >> 3)) & 7) << 3) + (col & 7);
}

// ---------------------------------------------------------------- casts + rope table, one launch
__global__ __launch_bounds__(256) void k_castall(
    const float* __restrict__ x,  const float* __restrict__ Wq,
    const float* __restrict__ Wk, const float* __restrict__ Wv,
    const float* __restrict__ Wo,
    u16* __restrict__ xb,  u16* __restrict__ wqb, u16* __restrict__ wkb,
    u16* __restrict__ wvb, u16* __restrict__ wob,
    const int* __restrict__ pos, float2* __restrict__ tab) {
  if (blockIdx.x >= 8192) {
    int t = (blockIdx.x - 8192) * 256 + threadIdx.x;   // 65536
    int s = t >> 5, i = t & 31;
    float p = (float)pos[s];
    float ang = p * powf(10000.0f, -(float)i / 32.0f);
    tab[t] = make_float2(cosf(ang), sinf(ang));
    return;
  }
  int i = blockIdx.x * 256 + threadIdx.x;        // 2M float4 total
  const float* s;
  u16* d;
  int off;
  if (i < 1048576) { s = x; d = xb; off = i; }
  else {
    int j = i - 1048576;
    int w = j >> 18;
    off = j & 262143;
    s = (w == 0) ? Wq : (w == 1) ? Wk : (w == 2) ? Wv : Wo;
    d = (w == 0) ? wqb : (w == 1) ? wkb : (w == 2) ? wvb : wob;
  }
  float4 v = reinterpret_cast<const float4*>(s)[off];
  ushort4 o;
  o.x = f2b(v.x); o.y = f2b(v.y); o.z = f2b(v.z); o.w = f2b(v.w);
  reinterpret_cast<ushort4*>(d)[off] = o;
}

// ---------------------------------------------------------------- RoPE apply on K only
__global__ __launch_bounds__(256) void k_ropeK(u16* __restrict__ K,
                                               const float2* __restrict__ tab) {
  int t = blockIdx.x * 256 + threadIdx.x;        // Mrows*Dm/8
  int row = t >> 7;
  int c0 = (t & 127) << 3;
  int i0 = (c0 & 63) >> 1;
  const float2* tb = &tab[(row & (Ss - 1)) * 32 + i0];
  float2 cs[4];
#pragma unroll
  for (int j = 0; j < 4; ++j) cs[j] = tb[j];
  size_t off = (size_t)row * Dm + c0;
  s16x8 k = *reinterpret_cast<const s16x8*>(&K[off]);
  s16x8 ko;
#pragma unroll
  for (int j = 0; j < 4; ++j) {
    float ke = b2f((u16)k[2 * j]), kd = b2f((u16)k[2 * j + 1]);
    ko[2 * j]     = (short)f2b(cs[j].x * ke - cs[j].y * kd);
    ko[2 * j + 1] = (short)f2b(cs[j].y * ke + cs[j].x * kd);
  }
  *reinterpret_cast<s16x8*>(&K[off]) = ko;
}

// ---------------------------------------------------------------- QKV GEMM, double-buffered
// 128x128 tile, BK=32, one barrier per iter. B = merged [3072][1024];
// epilogue routes by n0>>10 (0->Q, 1->K, 2->V transposed [b][e][s]).
__global__ __launch_bounds__(256) void k_gemm_qkv(
    const u16* __restrict__ A, const u16* __restrict__ B,
    u16* __restrict__ OQ, u16* __restrict__ OK2, u16* __restrict__ OVT) {
  constexpr int BN = 128, NFR = 4;
  __shared__ __align__(16) u16 lsA[2][128 * 32];
  __shared__ __align__(16) u16 lsB[2][BN * 32];
  const int tid = threadIdx.x, lane = tid & 63, wave = tid >> 6;
  const int quad = lane >> 4, l16 = lane & 15;
  const int wrow = wave >> 1, wcol = wave & 1;
  const int n0 = blockIdx.x * BN, m0 = blockIdx.y * 128;
  const int K = Dm;
  f32x4 acc[4][NFR] = {};

  auto stage = [&](int k0, int bi) {
#pragma unroll
    for (int c = 0; c < 2; ++c) {
      int f = (wave * 2 + c) * 64 + lane;
      int row = f >> 2;
      int gs = (f & 3) ^ ((row >> 1) & 3);
      GLDS(A + (size_t)(m0 + row) * K + k0 + gs * 8, &lsA[bi][(wave * 2 + c) * 512]);
    }
#pragma unroll
    for (int c = 0; c < 2; ++c) {
      int f = (wave * 2 + c) * 64 + lane;
      int row = f >> 2;
      int gs = (f & 3) ^ ((row >> 1) & 3);
      GLDS(B + (size_t)(n0 + row) * K + k0 + gs * 8, &lsB[bi][(wave * 2 + c) * 512]);
    }
  };

  stage(0, 0);
  int bi = 0;
  for (int k0 = 0; k0 < K; k0 += 32) {
    __syncthreads();
    if (k0 + 32 < K) stage(k0 + 32, bi ^ 1);
    s16x8 af[4], bfr[NFR];
#pragma unroll
    for (int i = 0; i < 4; ++i) {
      int row = wrow * 64 + i * 16 + l16;
      af[i] = *reinterpret_cast<const s16x8*>(
          &lsA[bi][row * 32 + ((quad ^ ((row >> 1) & 3)) << 3)]);
    }
#pragma unroll
    for (int i = 0; i < NFR; ++i) {
      int row = wcol * 64 + i * 16 + l16;
      bfr[i] = *reinterpret_cast<const s16x8*>(
          &lsB[bi][row * 32 + ((quad ^ ((row >> 1) & 3)) << 3)]);
    }
#pragma unroll
    for (int mi = 0; mi < 4; ++mi)
#pragma unroll
      for (int ni = 0; ni < NFR; ++ni)
        acc[mi][ni] = __builtin_amdgcn_mfma_f32_16x16x32_bf16(af[mi], bfr[ni], acc[mi][ni], 0, 0, 0);
    bi ^= 1;
  }

  const int which = n0 >> 10;
  const int nbase = (n0 & 1023) + wcol * 64;
  if (which == 2) {
#pragma unroll
    for (int mi = 0; mi < 4; ++mi)
#pragma unroll
      for (int ni = 0; ni < NFR; ++ni) {
        int row0 = m0 + wrow * 64 + mi * 16 + quad * 4;
        int col  = nbase + ni * 16 + l16;
        int bb = row0 >> 11, s0 = row0 & (Ss - 1);
        ushort4 pk;
        pk.x = f2b(acc[mi][ni][0]); pk.y = f2b(acc[mi][ni][1]);
        pk.z = f2b(acc[mi][ni][2]); pk.w = f2b(acc[mi][ni][3]);
        *reinterpret_cast<ushort4*>(&OVT[((size_t)bb * Dm + col) * Ss + s0]) = pk;
      }
  } else {
    u16* Op = which ? OK2 : OQ;
#pragma unroll
    for (int mi = 0; mi < 4; ++mi)
#pragma unroll
      for (int ni = 0; ni < NFR; ++ni)
#pragma unroll
        for (int r = 0; r < 4; ++r) {
          int row = m0 + wrow * 64 + mi * 16 + quad * 4 + r;
          int col = nbase + ni * 16 + l16;
          Op[(size_t)row * Dm + col] = f2b(acc[mi][ni][r]);
        }
  }
}

// ---------------------------------------------------------------- Wo GEMM: two-team split-K
// 512 threads = 2 teams x 4 waves. Team t accumulates K in [t*512,(t+1)*512)
// over its own double-buffered LDS; equal 16-iter loops share the barrier.
// Epilogue: team1 -> LDS scratch (fp32, 16B/lane contiguous), team0 adds and
// stores fp32. 16 waves/CU (vs 8 for the 256-thread version), no extra HBM.
__global__ __launch_bounds__(512) void k_wo(
    const u16* __restrict__ A, const u16* __restrict__ B,
    float* __restrict__ OF) {
  __shared__ __align__(16) u16 lsA[2][2][128 * 32];   // [team][buf], 32 KB
  __shared__ __align__(16) u16 lsB[2][2][64 * 32];    // [team][buf], 16 KB
  const int tid = threadIdx.x, lane = tid & 63, wave = tid >> 6;
  const int team = wave >> 2, wv = wave & 3;
  const int quad = lane >> 4, l16 = lane & 15;
  const int wrow = wv >> 1, wcol = wv & 1;
  const int n0 = blockIdx.x * 64, m0 = blockIdx.y * 128;
  const int kbase = team * 512;
  f32x4 acc[4][2] = {};

  auto stage = [&](int k0, int bi) {
#pragma unroll
    for (int c = 0; c < 2; ++c) {
      int f = (wv * 2 + c) * 64 + lane;        // 512 A chunks per team
      int row = f >> 2;
      int gs = (f & 3) ^ ((row >> 1) & 3);
      GLDS(A + (size_t)(m0 + row) * Dm + kbase + k0 + gs * 8,
           &lsA[team][bi][(wv * 2 + c) * 512]);
    }
    {
      int f = wv * 64 + lane;                  // 256 B chunks per team
      int row = f >> 2;
      int gs = (f & 3) ^ ((row >> 1) & 3);
      GLDS(B + (size_t)(n0 + row) * Dm + kbase + k0 + gs * 8,
           &lsB[team][bi][wv * 512]);
    }
  };

  stage(0, 0);
  int bi = 0;
  for (int k0 = 0; k0 < 512; k0 += 32) {
    __syncthreads();
    if (k0 + 32 < 512) stage(k0 + 32, bi ^ 1);
    s16x8 af[4], bfr[2];
#pragma unroll
    for (int i = 0; i < 4; ++i) {
      int row = wrow * 64 + i * 16 + l16;
      af[i] = *reinterpret_cast<const s16x8*>(
          &lsA[team][bi][row * 32 + ((quad ^ ((row >> 1) & 3)) << 3)]);
    }
#pragma unroll
    for (int i = 0; i < 2; ++i) {
      int row = wcol * 32 + i * 16 + l16;
      bfr[i] = *reinterpret_cast<const s16x8*>(
          &lsB[team][bi][row * 32 + ((quad ^ ((row >> 1) & 3)) << 3)]);
    }
#pragma unroll
    for (int mi = 0; mi < 4; ++mi)
#pragma unroll
      for (int ni = 0; ni < 2; ++ni)
        acc[mi][ni] = __builtin_amdgcn_mfma_f32_16x16x32_bf16(af[mi], bfr[ni], acc[mi][ni], 0, 0, 0);
    bi ^= 1;
  }

  // cross-team reduction through LDS (reuse lsA as 32 KB fp32 scratch)
  __syncthreads();
  float* scr = (float*)&lsA[0][0][0];
  const int ttid = tid & 255;
  if (team == 1) {
#pragma unroll
    for (int mi = 0; mi < 4; ++mi)
#pragma unroll
      for (int ni = 0; ni < 2; ++ni)
        *reinterpret_cast<f32x4*>(&scr[(mi * 2 + ni) * 1024 + ttid * 4]) = acc[mi][ni];
  }
  __syncthreads();
  if (team == 0) {
#pragma unroll
    for (int mi = 0; mi < 4; ++mi)
#pragma unroll
      for (int ni = 0; ni < 2; ++ni) {
        f32x4 other = *reinterpret_cast<const f32x4*>(&scr[(mi * 2 + ni) * 1024 + ttid * 4]);
        f32x4 v = acc[mi][ni] + other;
#pragma unroll
        for (int r = 0; r < 4; ++r) {
          int row = m0 + wrow * 64 + mi * 16 + quad * 4 + r;
          int col = n0 + wcol * 32 + ni * 16 + l16;
          OF[(size_t)row * Dm + col] = v[r];
        }
      }
  }
}

// ---------------------------------------------------------------- flash attention (causal)
// Round-10 structure (proven fastest): transposed compute, 128-q blocks,
// 32 q/wave, static-max exp2 softmax, PAIR-staged 4-slot ring (one barrier
// per 128 keys), balanced causal map, Q-RoPE fused into fragment load.
__global__ __launch_bounds__(256) void k_flash(const u16* __restrict__ Q,
                                               const u16* __restrict__ K,
                                               const u16* __restrict__ VT,
                                               u16* __restrict__ O,
                                               const float2* __restrict__ tab) {
  __shared__ __align__(16) u16 lsK[4][64 * 64];    // [slot][key][dk], SW64
  __shared__ __align__(16) u16 lsVT[4][64 * 64];   // [slot][dk][key], SW64
  __shared__ __align__(16) u16 lsP[4][32 * 64];    // per-wave P^T [q][key], chunk-xor
  const int tid = threadIdx.x, lane = tid & 63, wave = tid >> 6;
  const int quad = lane >> 4, l16 = lane & 15;
  const int bid = blockIdx.x;                      // 512 blocks
  const int bh = bid & 31;
  const int h = bh & (H_ - 1), b = bh >> 4;
  const int g = bid >> 5, a = g & 7, bsel = g >> 3;
  const int qt = bsel ? (15 - a) : a;              // balanced causal map
  const int q0 = qt * 128;
  const int qbase = q0 + wave * 32;
  const int ktmax_w = (qbase + 31) >> 6;
  const int xorv = (l16 * 2) & 0xE;

  // Q frags with fused RoPE (+QSCALE): 4 in-lane even/odd pairs per 8-dk chunk
  s16x8 qf[2][2];
#pragma unroll
  for (int s = 0; s < 2; ++s) {
    const int qpos = qbase + s * 16 + l16;
    const size_t qoff = (size_t)(b * Ss + qpos) * Dm + h * 64;
    s16x8 r0 = *reinterpret_cast<const s16x8*>(&Q[qoff + quad * 8]);
    s16x8 r1 = *reinterpret_cast<const s16x8*>(&Q[qoff + 32 + quad * 8]);
    const float2* tb = &tab[(qpos & (Ss - 1)) * 32];
#pragma unroll
    for (int kc = 0; kc < 2; ++kc) {
      s16x8 raw = kc ? r1 : r0;
#pragma unroll
      for (int p = 0; p < 4; ++p) {
        float2 cs = tb[kc * 16 + quad * 4 + p];
        float e = b2f((u16)raw[2 * p]), o = b2f((u16)raw[2 * p + 1]);
        qf[s][kc][2 * p]     = (short)f2b((cs.x * e - cs.y * o) * QSCALE);
        qf[s][kc][2 * p + 1] = (short)f2b((cs.y * e + cs.x * o) * QSCALE);
      }
    }
  }
  s16x8 ones;
#pragma unroll
  for (int j = 0; j < 8; ++j) ones[j] = (short)0x3F80;   // bf16 1.0

  f32x4 ot[2][4] = {};
  f32x4 lAcc[2] = {};

  auto stagepair = [&](int pp) {
#pragma unroll
    for (int half = 0; half < 2; ++half) {
      const int kt = pp * 2 + half;
      const int slot = kt & 3;
      const size_t kbase  = (size_t)(b * Ss + kt * 64) * Dm + h * 64;
      const size_t vtbase = ((size_t)b * Dm + h * 64) * Ss + kt * 64;
#pragma unroll
      for (int c = 0; c < 2; ++c) {
        int sl = (wave * 2 + c) * 64 + lane;
        int row = sl >> 3;
        int gg = ((sl & 7) ^ (row & 7) ^ (row >> 3)) & 7;
        GLDS(K  + kbase  + (size_t)row * Dm + gg * 8, &lsK[slot][(wave * 2 + c) * 512]);
        GLDS(VT + vtbase + (size_t)row * Ss + gg * 8, &lsVT[slot][(wave * 2 + c) * 512]);
      }
    }
  };

  stagepair(0);
  for (int pp = 0; pp <= qt; ++pp) {
    __syncthreads();
    if (pp < qt) stagepair(pp + 1);
    const int kt0 = 2 * pp;

    f32x4 st[2][2][4] = {};   // [half][qgroup][ni]
#pragma unroll
    for (int half = 0; half < 2; ++half) {
      const int kt = kt0 + half;
      if (kt > ktmax_w) break;
      const int slot = kt & 3;
#pragma unroll
      for (int kc = 0; kc < 2; ++kc)
#pragma unroll
        for (int ni = 0; ni < 4; ++ni) {
          s16x8 kf = *reinterpret_cast<const s16x8*>(
              &lsK[slot][SW64(ni * 16 + l16, kc * 32 + quad * 8)]);
          st[half][0][ni] = __builtin_amdgcn_mfma_f32_16x16x32_bf16(kf, qf[0][kc], st[half][0][ni], 0, 0, 0);
          st[half][1][ni] = __builtin_amdgcn_mfma_f32_16x16x32_bf16(kf, qf[1][kc], st[half][1][ni], 0, 0, 0);
        }
    }
#pragma unroll
    for (int half = 0; half < 2; ++half) {
      const int kt = kt0 + half;
      if (kt > ktmax_w) break;
      const int slot = kt & 3;
      if (kt == ktmax_w) {   // causal mask on diagonal tile: key > q
#pragma unroll
        for (int s = 0; s < 2; ++s) {
          int gq = qbase + s * 16 + l16;
#pragma unroll
          for (int ni = 0; ni < 4; ++ni)
#pragma unroll
            for (int r = 0; r < 4; ++r)
              if (kt * 64 + ni * 16 + quad * 4 + r > gq) st[half][s][ni][r] = -INFINITY;
        }
      }
#pragma unroll
      for (int s = 0; s < 2; ++s)
#pragma unroll
        for (int ni = 0; ni < 4; ++ni) {
          float e0 = __builtin_amdgcn_exp2f(st[half][s][ni][0]);
          float e1 = __builtin_amdgcn_exp2f(st[half][s][ni][1]);
          float e2 = __builtin_amdgcn_exp2f(st[half][s][ni][2]);
          float e3 = __builtin_amdgcn_exp2f(st[half][s][ni][3]);
          uint2 pk;
          pk.x = pkbf(e1, e0);
          pk.y = pkbf(e3, e2);
          *reinterpret_cast<uint2*>(
              &lsP[wave][(s * 16 + l16) * 64 + (((ni * 4 + quad) ^ xorv) << 2)]) = pk;
        }
#pragma unroll
      for (int kc = 0; kc < 2; ++kc) {
        s16x8 pf0 = *reinterpret_cast<const s16x8*>(
            &lsP[wave][l16 * 64 + (((kc * 8 + quad * 2) ^ xorv) << 2)]);
        s16x8 pf1 = *reinterpret_cast<const s16x8*>(
            &lsP[wave][(16 + l16) * 64 + (((kc * 8 + quad * 2) ^ xorv) << 2)]);
        lAcc[0] = __builtin_amdgcn_mfma_f32_16x16x32_bf16(ones, pf0, lAcc[0], 0, 0, 0);
        lAcc[1] = __builtin_amdgcn_mfma_f32_16x16x32_bf16(ones, pf1, lAcc[1], 0, 0, 0);
#pragma unroll
        for (int ni = 0; ni < 4; ++ni) {
          s16x8 vf = *reinterpret_cast<const s16x8*>(
              &lsVT[slot][SW64(ni * 16 + l16, kc * 32 + quad * 8)]);
          ot[0][ni] = __builtin_amdgcn_mfma_f32_16x16x32_bf16(vf, pf0, ot[0][ni], 0, 0, 0);
          ot[1][ni] = __builtin_amdgcn_mfma_f32_16x16x32_bf16(vf, pf1, ot[1][ni], 0, 0, 0);
        }
      }
    }
  }

  // epilogue: O[q][dk], 4 consecutive dk per lane -> 8B stores
#pragma unroll
  for (int s = 0; s < 2; ++s) {
    float inv = 1.0f / lAcc[s][0];
    const size_t obase = (size_t)(b * Ss + qbase + s * 16 + l16) * Dm + h * 64;
#pragma unroll
    for (int ni = 0; ni < 4; ++ni) {
      ushort4 pk;
      pk.x = f2b(ot[s][ni][0] * inv); pk.y = f2b(ot[s][ni][1] * inv);
      pk.z = f2b(ot[s][ni][2] * inv); pk.w = f2b(ot[s][ni][3] * inv);
      *reinterpret_cast<ushort4*>(&O[obase + ni * 16 + quad * 4]) = pk;
    }
  }
}

// ---------------------------------------------------------------- launch
extern "C" void kernel_launch(void* const* d_in, const int* in_sizes, int n_in,
                              void* d_out, int out_size, void* d_ws, size_t ws_size,
                              hipStream_t stream) {
  const float* x  = (const float*)d_in[0];
  const float* Wq = (const float*)d_in[1];
  const float* Wk = (const float*)d_in[2];
  const float* Wv = (const float*)d_in[3];
  const float* Wo = (const float*)d_in[4];
  const int* pos  = (const int*)d_in[5];
  float* out = (float*)d_out;

  char* w = (char*)d_ws;
  u16* xb  = (u16*)w; w += (size_t)Mrows * Dm * 2;
  u16* wqb = (u16*)w; w += (size_t)Dm * Dm * 2;   // wqb/wkb/wvb contiguous:
  u16* wkb = (u16*)w; w += (size_t)Dm * Dm * 2;   // merged [3072][1024] B matrix
  u16* wvb = (u16*)w; w += (size_t)Dm * Dm * 2;
  u16* wob = (u16*)w; w += (size_t)Dm * Dm * 2;
  u16* Qb  = (u16*)w; w += (size_t)Mrows * Dm * 2;
  u16* Kb  = (u16*)w; w += (size_t)Mrows * Dm * 2;
  u16* VTb = (u16*)w; w += (size_t)Mrows * Dm * 2;   // V transposed [b][e][s]
  u16* Ab  = (u16*)w; w += (size_t)Mrows * Dm * 2;
  float2* tabf = (float2*)w; w += (size_t)Ss * 32 * sizeof(float2);

  // casts + rope table in one launch
  k_castall<<<8448, 256, 0, stream>>>(x, Wq, Wk, Wv, Wo, xb, wqb, wkb, wvb, wob,
                                      pos, tabf);
  // merged QKV projection: B=[3072][1024], epilogue routes Q/K/V^T by n-tile
  k_gemm_qkv<<<dim3(24, 32), 256, 0, stream>>>(xb, wqb, Qb, Kb, VTb);
  // RoPE on K only (Q's RoPE fused into flash)
  k_ropeK<<<Mrows * Dm / 8 / 256, 256, 0, stream>>>(Kb, tabf);
  // flash attention (round-10 pair-staged structure)
  k_flash<<<dim3(512), 256, 0, stream>>>(Qb, Kb, VTb, Ab, tabf);
  // output projection: two-team split-K, fp32 epilogue
  k_wo<<<dim3(16, 32), 512, 0, stream>>>(Ab, wob, out);
}